// Round 3
// baseline (268.161 us; speedup 1.0000x reference)
//
#include <hip/hip_runtime.h>
#include <hip/hip_bf16.h>
#include <math.h>

#define BATCH 8
#define CIN   384
#define HEADS 12
#define HGT   56
#define WID   56
#define HW    3136                 // 56*56
#define NPIX  (BATCH*HW)           // 25088
#define K4H   972                  // 3^4 * 12
#define K4HP  1024                 // padded N for A-GEMM

typedef __bf16 bf16x8 __attribute__((ext_vector_type(8)));
typedef float f32x4 __attribute__((ext_vector_type(4)));
typedef __hip_bfloat16 hbf16;

__device__ __forceinline__ void gload_lds16(const void* g, void* l) {
  __builtin_amdgcn_global_load_lds(
      (const __attribute__((address_space(1))) void*)g,
      (__attribute__((address_space(3))) void*)l, 16, 0, 0);
}

// ---------------------------------------------------------------------------
// transpose+convert: x [B, C, HW] f32 -> xb [B*HW, C] bf16
// ---------------------------------------------------------------------------
__global__ __launch_bounds__(256) void conv_x(const float* __restrict__ x,
                                              hbf16* __restrict__ xb)
{
  __shared__ float s[32][33];
  const int b   = blockIdx.z;
  const int hw0 = blockIdx.x * 32;
  const int c0  = blockIdx.y * 32;
  const int tx = threadIdx.x & 31, ty = threadIdx.x >> 5;   // 32x8
  #pragma unroll
  for (int i = 0; i < 4; i++) {
    int c = c0 + ty + i * 8;
    s[ty + i * 8][tx] = x[((size_t)b * CIN + c) * HW + hw0 + tx]; // s[c_l][hw_l]
  }
  __syncthreads();
  #pragma unroll
  for (int i = 0; i < 4; i++) {
    int hw = hw0 + ty + i * 8;
    xb[((size_t)b * HW + hw) * CIN + c0 + tx] = __float2bfloat16(s[tx][ty + i * 8]);
  }
}

// ---------------------------------------------------------------------------
// outf [NPIX, C] f32 -> out [B, C, HW] f32 (bias already added)
// ---------------------------------------------------------------------------
__global__ __launch_bounds__(256) void trans_out(const float* __restrict__ of,
                                                 float* __restrict__ out)
{
  __shared__ float s[32][33];
  const int b   = blockIdx.z;
  const int hw0 = blockIdx.x * 32;
  const int c0  = blockIdx.y * 32;
  const int tx = threadIdx.x & 31, ty = threadIdx.x >> 5;
  #pragma unroll
  for (int i = 0; i < 4; i++) {
    int hw = hw0 + ty + i * 8;
    s[ty + i * 8][tx] = of[((size_t)b * HW + hw) * CIN + c0 + tx]; // s[hw_l][c_l]
  }
  __syncthreads();
  #pragma unroll
  for (int i = 0; i < 4; i++) {
    int c = c0 + ty + i * 8;
    out[((size_t)b * CIN + c) * HW + hw0 + tx] = s[tx][ty + i * 8];
  }
}

// ---------------------------------------------------------------------------
// weight convert (+ zero-pad rows up to rows_dst): src [rows_src, CIN] f32
// ---------------------------------------------------------------------------
__global__ __launch_bounds__(256) void conv_w(const float* __restrict__ w,
                                              hbf16* __restrict__ wb,
                                              int rows_src, int total)
{
  int i = blockIdx.x * 256 + threadIdx.x;
  if (i >= total) return;
  int n = i / CIN;
  wb[i] = (n < rows_src) ? __float2bfloat16(w[i]) : __float2bfloat16(0.f);
}

// ---------------------------------------------------------------------------
// MFMA GEMM: out[m,n] = sum_k A[m,k]*Bt[n,k] (+bias[n]), OUT = float or bf16
// A: [M=NPIX, 384] bf16 row-major. Bt: [Npad, 384] bf16 row-major (padded).
// 128x128 tile, BK=32, 4 waves (2x2 of 64x64), mfma_f32_16x16x32_bf16.
// ---------------------------------------------------------------------------
template<int NLOG, int HASBIAS, typename OUT>
__global__ __launch_bounds__(256) void gemm_mfma(
    const hbf16* __restrict__ A_,
    const hbf16* __restrict__ Bt_,
    const float* __restrict__ bias,
    OUT* __restrict__ outp)
{
  __shared__ __bf16 As[128 * 32];
  __shared__ __bf16 Bs[128 * 32];
  const __bf16* A  = (const __bf16*)A_;
  const __bf16* Bt = (const __bf16*)Bt_;

  const int tid  = threadIdx.x;
  const int wave = tid >> 6, lane = tid & 63;
  const int wr = wave >> 1, wc = wave & 1;
  const int l16 = lane & 15, kg = lane >> 4;
  const int m0 = blockIdx.x * 128, n0 = blockIdx.y * 128;

  const int srow = tid >> 2;              // (tid*16)>>6
  const int skb  = (tid & 3) * 16;        // byte offset within 64B row

  f32x4 acc[4][4] = {};

  for (int k0 = 0; k0 < CIN; k0 += 32) {
    const char* gA = (const char*)(A  + (size_t)m0 * CIN + k0);
    const char* gB = (const char*)(Bt + (size_t)n0 * CIN + k0);
    #pragma unroll
    for (int p = 0; p < 2; p++) {
      int row = p * 64 + srow;
      gload_lds16(gA + (size_t)row * (CIN * 2) + skb,
                  (char*)As + p * 4096 + wave * 1024);
      gload_lds16(gB + (size_t)row * (CIN * 2) + skb,
                  (char*)Bs + p * 4096 + wave * 1024);
    }
    __syncthreads();

    bf16x8 af[4], bfr[4];
    #pragma unroll
    for (int mi = 0; mi < 4; mi++)
      af[mi] = *(const bf16x8*)(As + (wr * 64 + mi * 16 + l16) * 32 + kg * 8);
    #pragma unroll
    for (int ni = 0; ni < 4; ni++)
      bfr[ni] = *(const bf16x8*)(Bs + (wc * 64 + ni * 16 + l16) * 32 + kg * 8);
    #pragma unroll
    for (int mi = 0; mi < 4; mi++)
      #pragma unroll
      for (int ni = 0; ni < 4; ni++)
        acc[mi][ni] = __builtin_amdgcn_mfma_f32_16x16x32_bf16(
            af[mi], bfr[ni], acc[mi][ni], 0, 0, 0);
    __syncthreads();
  }

  #pragma unroll
  for (int mi = 0; mi < 4; mi++) {
    #pragma unroll
    for (int ni = 0; ni < 4; ni++) {
      int n = n0 + wc * 64 + ni * 16 + l16;
      if (n < NLOG) {
        float bv = HASBIAS ? bias[n] : 0.f;
        #pragma unroll
        for (int r = 0; r < 4; r++) {
          int m = m0 + wr * 64 + mi * 16 + kg * 4 + r;
          float v = acc[mi][ni][r] + bv;
          if constexpr (sizeof(OUT) == 2)
            outp[(size_t)m * NLOG + n] = __float2bfloat16(v);
          else
            outp[(size_t)m * NLOG + n] = v;
        }
      }
    }
  }
}

// ---------------------------------------------------------------------------
// Fused softmax + attention apply + fold (gather form), bf16 in/out.
// Each attn logit row [center, n, p, 0..8] is consumed by exactly ONE output
// pixel, so softmax fuses here with no duplicated work.
// folded[b,y,x,c] = sum_{i,j (center valid)} sum_{i',j'}
//     softmax_q(A[b, center=(y-i+1,x-j+1), n, p=(i,j), :])[q=(i',j')]
//   * vproj[b, h=x+j'-j, w=y+i'-i, c]            (spatial-transpose quirk)
// ---------------------------------------------------------------------------
__global__ __launch_bounds__(384) void apply_fold(
    const hbf16* __restrict__ attnb,   // [B*HW, 12, 9, 9] bf16 logits
    const hbf16* __restrict__ vprojb,  // [B*HW, C] bf16
    hbf16* __restrict__ foldedb)       // [B*HW, C] bf16
{
  const int pix = blockIdx.x;
  const int b = pix / HW;
  const int yx = pix % HW;
  const int y = yx / WID, x = yx % WID;

  __shared__ float Asm[HEADS * 81];    // [n][center(i,j)][q], post-softmax

  const int tid = threadIdx.x;
  if (tid < HEADS * 9) {
    const int n = tid / 9, ct = tid % 9;
    const int i = ct / 3, j = ct % 3;
    const int hh = y - i + 1, ww = x - j + 1;
    const bool valid = (hh >= 0 && hh < HGT && ww >= 0 && ww < WID);
    float v[9];
    if (valid) {
      const hbf16* p = attnb +
          (((size_t)b * HW + hh * WID + ww) * HEADS + n) * 81 + ct * 9;
      const float scale = 0.17677669529663687f; // 32^-0.5
      float m = -1e30f;
      #pragma unroll
      for (int q = 0; q < 9; q++) {
        v[q] = __bfloat162float(p[q]) * scale;
        m = fmaxf(m, v[q]);
      }
      float s = 0.f;
      #pragma unroll
      for (int q = 0; q < 9; q++) { v[q] = __expf(v[q] - m); s += v[q]; }
      float inv = 1.f / s;
      #pragma unroll
      for (int q = 0; q < 9; q++) v[q] *= inv;
    } else {
      #pragma unroll
      for (int q = 0; q < 9; q++) v[q] = 0.f;
    }
    #pragma unroll
    for (int q = 0; q < 9; q++) Asm[tid * 9 + q] = v[q];
  }
  __syncthreads();

  const int c = tid;
  const int n = c >> 5;

  float vr[5][5];
  #pragma unroll
  for (int a = 0; a < 5; a++) {
    int wi = y + a - 2;
    #pragma unroll
    for (int e = 0; e < 5; e++) {
      int hi = x + e - 2;
      vr[a][e] = (wi >= 0 && wi < WID && hi >= 0 && hi < HGT)
          ? __bfloat162float(vprojb[((size_t)b * HW + hi * WID + wi) * CIN + c])
          : 0.f;
    }
  }

  float acc = 0.f;
  const float* An = &Asm[n * 81];
  #pragma unroll
  for (int i = 0; i < 3; i++)
    #pragma unroll
    for (int j = 0; j < 3; j++)
      #pragma unroll
      for (int ip = 0; ip < 3; ip++)
        #pragma unroll
        for (int jp = 0; jp < 3; jp++)
          acc += An[(i * 3 + j) * 9 + ip * 3 + jp] * vr[2 + ip - i][2 + jp - j];

  foldedb[(size_t)pix * CIN + c] = __float2bfloat16(acc);
}

// ---------------------------------------------------------------------------
extern "C" void kernel_launch(void* const* d_in, const int* in_sizes, int n_in,
                              void* d_out, int out_size, void* d_ws, size_t ws_size,
                              hipStream_t stream)
{
  const float* x  = (const float*)d_in[0];
  const float* Wv = (const float*)d_in[1];
  const float* Wa = (const float*)d_in[2];
  const float* ba = (const float*)d_in[3];
  const float* Wp = (const float*)d_in[4];
  const float* bp = (const float*)d_in[5];
  float* out = (float*)d_out;

  char* w = (char*)d_ws;
  const size_t ATTN_B  = (size_t)NPIX * K4H * 2;   // 48.8 MB bf16 (reused as outf f32: 38.5MB)
  const size_t VPROJ_B = (size_t)NPIX * CIN * 2;   // 19.3 MB bf16
  const size_t XB_B    = (size_t)NPIX * CIN * 2;   // 19.3 MB (reused as foldedb)
  hbf16* attnb  = (hbf16*)w;
  hbf16* vprojb = (hbf16*)(w + ATTN_B);
  hbf16* xb     = (hbf16*)(w + ATTN_B + VPROJ_B);
  hbf16* wvb    = (hbf16*)(w + ATTN_B + VPROJ_B + XB_B);
  hbf16* wab    = wvb + (size_t)CIN * CIN;
  hbf16* wpb    = wab + (size_t)K4HP * CIN;
  hbf16* foldedb = xb;            // reuse: xb dead after the two input GEMMs
  float* outf    = (float*)attnb; // reuse: attnb dead after apply_fold

  // 1) input transpose/convert + weight converts
  conv_x<<<dim3(HW / 32, CIN / 32, BATCH), 256, 0, stream>>>(x, xb);
  conv_w<<<dim3((CIN * CIN + 255) / 256), 256, 0, stream>>>(Wv, wvb, CIN, CIN * CIN);
  conv_w<<<dim3((K4HP * CIN + 255) / 256), 256, 0, stream>>>(Wa, wab, K4H, K4HP * CIN);
  conv_w<<<dim3((CIN * CIN + 255) / 256), 256, 0, stream>>>(Wp, wpb, CIN, CIN * CIN);

  // 2) value projection: vprojb [pix, 384] bf16
  gemm_mfma<CIN, 0, hbf16><<<dim3(NPIX / 128, CIN / 128), 256, 0, stream>>>(
      xb, wvb, nullptr, vprojb);
  // 3) attention logits: attnb [pix, 972] bf16 (+ba)
  gemm_mfma<K4H, 1, hbf16><<<dim3(NPIX / 128, K4HP / 128), 256, 0, stream>>>(
      xb, wab, ba, attnb);
  // 4) fused softmax + attention apply + fold -> foldedb bf16
  apply_fold<<<dim3(NPIX), dim3(384), 0, stream>>>(attnb, vprojb, foldedb);
  // 5) output projection (+bp): outf [pix, 384] f32
  gemm_mfma<CIN, 1, float><<<dim3(NPIX / 128, CIN / 128), 256, 0, stream>>>(
      foldedb, wpb, bp, outf);
  // 6) transpose to [B, C, H, W]
  trans_out<<<dim3(HW / 32, CIN / 32, BATCH), 256, 0, stream>>>(outf, out);
}

// Round 4
// 186.849 us; speedup vs baseline: 1.4352x; 1.4352x over previous
//
#include <hip/hip_runtime.h>
#include <hip/hip_bf16.h>
#include <math.h>

#define BATCH 8
#define CIN   384
#define HEADS 12
#define HGT   56
#define WID   56
#define HW    3136                 // 56*56
#define NPIX  (BATCH*HW)           // 25088
#define K4H   972                  // 3^4 * 12
#define K4HP  1024                 // padded N for A-GEMM
#define PIXB  8                    // pixels per apply_fold block

typedef __bf16 bf16x8 __attribute__((ext_vector_type(8)));
typedef float f32x4 __attribute__((ext_vector_type(4)));
typedef __hip_bfloat16 hbf16;

__device__ __forceinline__ void gload_lds16(const void* g, void* l) {
  __builtin_amdgcn_global_load_lds(
      (const __attribute__((address_space(1))) void*)g,
      (__attribute__((address_space(3))) void*)l, 16, 0, 0);
}

// ---------------------------------------------------------------------------
// transpose+convert: x [B, C, HW] f32 -> xb [B*HW, C] bf16
// ---------------------------------------------------------------------------
__global__ __launch_bounds__(256) void conv_x(const float* __restrict__ x,
                                              hbf16* __restrict__ xb)
{
  __shared__ float s[32][33];
  const int b   = blockIdx.z;
  const int hw0 = blockIdx.x * 32;
  const int c0  = blockIdx.y * 32;
  const int tx = threadIdx.x & 31, ty = threadIdx.x >> 5;   // 32x8
  #pragma unroll
  for (int i = 0; i < 4; i++) {
    int c = c0 + ty + i * 8;
    s[ty + i * 8][tx] = x[((size_t)b * CIN + c) * HW + hw0 + tx]; // s[c_l][hw_l]
  }
  __syncthreads();
  #pragma unroll
  for (int i = 0; i < 4; i++) {
    int hw = hw0 + ty + i * 8;
    xb[((size_t)b * HW + hw) * CIN + c0 + tx] = __float2bfloat16(s[tx][ty + i * 8]);
  }
}

// ---------------------------------------------------------------------------
// weight convert (+ zero-pad rows up to rows_dst): src [rows_src, CIN] f32
// ---------------------------------------------------------------------------
__global__ __launch_bounds__(256) void conv_w(const float* __restrict__ w,
                                              hbf16* __restrict__ wb,
                                              int rows_src, int total)
{
  int i = blockIdx.x * 256 + threadIdx.x;
  if (i >= total) return;
  int n = i / CIN;
  wb[i] = (n < rows_src) ? __float2bfloat16(w[i]) : __float2bfloat16(0.f);
}

// ---------------------------------------------------------------------------
// MFMA GEMM: out[m,n] = sum_k A[m,k]*Bt[n,k] (+bias[n])
// A: [M=NPIX, 384] bf16 row-major. Bt: [Npad, 384] bf16 row-major (padded).
// 128x128 tile, BK=32, 4 waves (2x2 of 64x64), mfma_f32_16x16x32_bf16.
// OUTMODE 0: f32 row-major [M, NLOG]; 1: bf16 row-major [M, NLOG];
//         2: f32 transposed to [B, NLOG, HW] (float4 store over contiguous m)
// ---------------------------------------------------------------------------
template<int NLOG, int HASBIAS, int OUTMODE>
__global__ __launch_bounds__(256) void gemm_mfma(
    const hbf16* __restrict__ A_,
    const hbf16* __restrict__ Bt_,
    const float* __restrict__ bias,
    void* __restrict__ outp)
{
  __shared__ __bf16 As[128 * 32];
  __shared__ __bf16 Bs[128 * 32];
  const __bf16* A  = (const __bf16*)A_;
  const __bf16* Bt = (const __bf16*)Bt_;

  const int tid  = threadIdx.x;
  const int wave = tid >> 6, lane = tid & 63;
  const int wr = wave >> 1, wc = wave & 1;
  const int l16 = lane & 15, kg = lane >> 4;
  const int m0 = blockIdx.x * 128, n0 = blockIdx.y * 128;

  const int srow = tid >> 2;              // (tid*16)>>6
  const int skb  = (tid & 3) * 16;        // byte offset within 64B row

  f32x4 acc[4][4] = {};

  for (int k0 = 0; k0 < CIN; k0 += 32) {
    const char* gA = (const char*)(A  + (size_t)m0 * CIN + k0);
    const char* gB = (const char*)(Bt + (size_t)n0 * CIN + k0);
    #pragma unroll
    for (int p = 0; p < 2; p++) {
      int row = p * 64 + srow;
      gload_lds16(gA + (size_t)row * (CIN * 2) + skb,
                  (char*)As + p * 4096 + wave * 1024);
      gload_lds16(gB + (size_t)row * (CIN * 2) + skb,
                  (char*)Bs + p * 4096 + wave * 1024);
    }
    __syncthreads();

    bf16x8 af[4], bfr[4];
    #pragma unroll
    for (int mi = 0; mi < 4; mi++)
      af[mi] = *(const bf16x8*)(As + (wr * 64 + mi * 16 + l16) * 32 + kg * 8);
    #pragma unroll
    for (int ni = 0; ni < 4; ni++)
      bfr[ni] = *(const bf16x8*)(Bs + (wc * 64 + ni * 16 + l16) * 32 + kg * 8);
    #pragma unroll
    for (int mi = 0; mi < 4; mi++)
      #pragma unroll
      for (int ni = 0; ni < 4; ni++)
        acc[mi][ni] = __builtin_amdgcn_mfma_f32_16x16x32_bf16(
            af[mi], bfr[ni], acc[mi][ni], 0, 0, 0);
    __syncthreads();
  }

  #pragma unroll
  for (int mi = 0; mi < 4; mi++) {
    #pragma unroll
    for (int ni = 0; ni < 4; ni++) {
      int n = n0 + wc * 64 + ni * 16 + l16;
      if (n < NLOG) {
        float bv = HASBIAS ? bias[n] : 0.f;
        if (OUTMODE == 2) {
          // 4 consecutive m = contiguous hw (4 | 3136 so no batch straddle)
          int m = m0 + wr * 64 + mi * 16 + kg * 4;
          int b = m / HW, hw = m % HW;
          f32x4 v;
          #pragma unroll
          for (int r = 0; r < 4; r++) v[r] = acc[mi][ni][r] + bv;
          *(f32x4*)((float*)outp + ((size_t)b * NLOG + n) * HW + hw) = v;
        } else {
          #pragma unroll
          for (int r = 0; r < 4; r++) {
            int m = m0 + wr * 64 + mi * 16 + kg * 4 + r;
            float v = acc[mi][ni][r] + bv;
            if (OUTMODE == 1)
              ((hbf16*)outp)[(size_t)m * NLOG + n] = __float2bfloat16(v);
            else
              ((float*)outp)[(size_t)m * NLOG + n] = v;
          }
        }
      }
    }
  }
}

// ---------------------------------------------------------------------------
// build_w: collapse softmax(attn) into a 5x5 effective kernel per (pixel,head)
// W[pix][n][a*5+e] = sum_{i,j valid center} softmax_q(logits[center,p=(i,j)])
//                    [q=(i+a-2)*3+(j+e-2)]  (terms with q offsets in range)
// One thread per (pixel, head).
// ---------------------------------------------------------------------------
__global__ __launch_bounds__(256) void build_w(
    const hbf16* __restrict__ attnb,   // [NPIX, 12, 81] bf16 logits
    float* __restrict__ Wg)            // [NPIX, 12, 25] f32
{
  int idx = blockIdx.x * 256 + threadIdx.x;
  if (idx >= NPIX * HEADS) return;
  const int pix = idx / HEADS, n = idx % HEADS;
  const int b = pix / HW, yx = pix % HW;
  const int y = yx / WID, x = yx % WID;

  float W[25];
  #pragma unroll
  for (int k = 0; k < 25; k++) W[k] = 0.f;
  const float scale = 0.17677669529663687f; // 32^-0.5

  #pragma unroll
  for (int i = 0; i < 3; i++) {
    #pragma unroll
    for (int j = 0; j < 3; j++) {
      const int hh = y - i + 1, ww = x - j + 1;
      if (hh < 0 || hh >= HGT || ww < 0 || ww >= WID) continue;
      const hbf16* p = attnb +
          (((size_t)b * HW + hh * WID + ww) * HEADS + n) * 81 + (i * 3 + j) * 9;
      float v[9];
      float m = -1e30f;
      #pragma unroll
      for (int q = 0; q < 9; q++) {
        v[q] = __bfloat162float(p[q]) * scale;
        m = fmaxf(m, v[q]);
      }
      float s = 0.f;
      #pragma unroll
      for (int q = 0; q < 9; q++) { v[q] = __expf(v[q] - m); s += v[q]; }
      const float inv = 1.f / s;
      #pragma unroll
      for (int ip = 0; ip < 3; ip++)
        #pragma unroll
        for (int jp = 0; jp < 3; jp++)
          W[(ip - i + 2) * 5 + (jp - j + 2)] += v[ip * 3 + jp] * inv;
    }
  }
  float* o = Wg + (size_t)idx * 25;
  #pragma unroll
  for (int k = 0; k < 25; k++) o[k] = W[k];
}

// ---------------------------------------------------------------------------
// apply_fold: folded[pix, c] = sum_{25} W[pix, head(c), a, e] * vproj[gather]
// Block = 8 pixels x 48 channel-groups (8 ch each). bf16x8 vector gathers.
// gather (spatial-transpose quirk): vr(a,e) = vprojb[b, hi=x+e-2, wi=y+a-2]
// with pixel index b*HW + hi*WID + wi.
// ---------------------------------------------------------------------------
__global__ __launch_bounds__(384) void apply_fold(
    const float* __restrict__ Wg,      // [NPIX, 12, 25]
    const hbf16* __restrict__ vprojb,  // [NPIX, C] bf16
    hbf16* __restrict__ foldedb)       // [NPIX, C] bf16
{
  __shared__ float Wl[PIXB * HEADS * 25];   // 2400 f32

  const int pix0 = blockIdx.x * PIXB;
  const int tid = threadIdx.x;
  for (int r = tid; r < PIXB * HEADS * 25; r += 384)
    Wl[r] = Wg[(size_t)pix0 * HEADS * 25 + r];
  __syncthreads();

  const int p8  = tid / 48;
  const int ch8 = tid % 48;
  const int c0  = ch8 * 8;
  const int n   = c0 >> 5;
  const int pix = pix0 + p8;            // 8 | 56 -> block stays in one row
  const int b = pix / HW, yx = pix % HW;
  const int y = yx / WID, x = yx % WID;

  const float* Wp = &Wl[(p8 * HEADS + n) * 25];
  float acc[8];
  #pragma unroll
  for (int k = 0; k < 8; k++) acc[k] = 0.f;

  #pragma unroll
  for (int a = 0; a < 5; a++) {
    const int wi = y + a - 2;
    #pragma unroll
    for (int e = 0; e < 5; e++) {
      const int hi = x + e - 2;
      if (wi >= 0 && wi < WID && hi >= 0 && hi < HGT) {
        const float w = Wp[a * 5 + e];
        const uint32_t* v = (const uint32_t*)(
            vprojb + ((size_t)b * HW + hi * WID + wi) * CIN + c0);
        #pragma unroll
        for (int u = 0; u < 4; u++) {
          uint32_t bits = v[u];
          float lo = __uint_as_float(bits << 16);
          float hif = __uint_as_float(bits & 0xffff0000u);
          acc[2 * u]     += w * lo;
          acc[2 * u + 1] += w * hif;
        }
      }
    }
  }

  bf16x8 o;
  #pragma unroll
  for (int k = 0; k < 8; k++) o[k] = (__bf16)__float2bfloat16(acc[k]);
  *(bf16x8*)(foldedb + (size_t)pix * CIN + c0) = o;
}

// ---------------------------------------------------------------------------
extern "C" void kernel_launch(void* const* d_in, const int* in_sizes, int n_in,
                              void* d_out, int out_size, void* d_ws, size_t ws_size,
                              hipStream_t stream)
{
  const float* x  = (const float*)d_in[0];
  const float* Wv = (const float*)d_in[1];
  const float* Wa = (const float*)d_in[2];
  const float* ba = (const float*)d_in[3];
  const float* Wp = (const float*)d_in[4];
  const float* bp = (const float*)d_in[5];
  float* out = (float*)d_out;

  char* w = (char*)d_ws;
  const size_t ATTN_B  = (size_t)NPIX * K4H * 2;       // 48.8 MB bf16
  const size_t VPROJ_B = (size_t)NPIX * CIN * 2;       // 19.3 MB bf16
  const size_t XB_B    = (size_t)NPIX * CIN * 2;       // 19.3 MB
  const size_t WG_B    = (size_t)NPIX * HEADS * 25 * 4; // 30.1 MB
  hbf16* attnb  = (hbf16*)w;
  hbf16* vprojb = (hbf16*)(w + ATTN_B);
  hbf16* xb     = (hbf16*)(w + ATTN_B + VPROJ_B);
  float* Wg     = (float*)(w + ATTN_B + VPROJ_B + XB_B);
  hbf16* wvb    = (hbf16*)(w + ATTN_B + VPROJ_B + XB_B + WG_B);
  hbf16* wab    = wvb + (size_t)CIN * CIN;
  hbf16* wpb    = wab + (size_t)K4HP * CIN;
  hbf16* foldedb = xb;            // reuse: xb dead after the two input GEMMs

  // 1) input transpose/convert + weight converts
  conv_x<<<dim3(HW / 32, CIN / 32, BATCH), 256, 0, stream>>>(x, xb);
  conv_w<<<dim3((CIN * CIN + 255) / 256), 256, 0, stream>>>(Wv, wvb, CIN, CIN * CIN);
  conv_w<<<dim3((K4HP * CIN + 255) / 256), 256, 0, stream>>>(Wa, wab, K4H, K4HP * CIN);
  conv_w<<<dim3((CIN * CIN + 255) / 256), 256, 0, stream>>>(Wp, wpb, CIN, CIN * CIN);

  // 2) value projection: vprojb [pix, 384] bf16
  gemm_mfma<CIN, 0, 1><<<dim3(NPIX / 128, CIN / 128), 256, 0, stream>>>(
      xb, wvb, nullptr, vprojb);
  // 3) attention logits: attnb [pix, 972] bf16 (+ba)
  gemm_mfma<K4H, 1, 1><<<dim3(NPIX / 128, K4HP / 128), 256, 0, stream>>>(
      xb, wab, ba, attnb);
  // 4) softmax + collapse to 5x5 effective kernels
  build_w<<<dim3((NPIX * HEADS + 255) / 256), 256, 0, stream>>>(attnb, Wg);
  // 5) apply 5x5 kernels to vproj -> foldedb bf16
  apply_fold<<<dim3(NPIX / PIXB), dim3(384), 0, stream>>>(Wg, vprojb, foldedb);
  // 6) output projection (+bp), fused transpose to [B, C, HW]
  gemm_mfma<CIN, 1, 2><<<dim3(NPIX / 128, CIN / 128), 256, 0, stream>>>(
      foldedb, wpb, bp, out);
}

// Round 5
// 170.938 us; speedup vs baseline: 1.5688x; 1.0931x over previous
//
#include <hip/hip_runtime.h>
#include <hip/hip_bf16.h>
#include <math.h>

#define BATCH 8
#define CIN   384
#define HEADS 12
#define HGT   56
#define WID   56
#define HW    3136                 // 56*56
#define NPIX  (BATCH*HW)           // 25088
#define NVAL  384
#define NATT  972
#define NQKV  1408                 // 384 + 972 padded to 11*128
#define ASTRIDE 976                // attn row stride (bf16), 16B-aligned
#define PIXB  8
#define KSTEPS (CIN/32)            // 12

typedef __bf16 bf16x8 __attribute__((ext_vector_type(8)));
typedef __bf16 bf16x4 __attribute__((ext_vector_type(4)));
typedef float f32x4 __attribute__((ext_vector_type(4)));
typedef __hip_bfloat16 hbf16;

__device__ __forceinline__ void gload_lds16(const void* g, void* l) {
  __builtin_amdgcn_global_load_lds(
      (const __attribute__((address_space(1))) void*)g,
      (__attribute__((address_space(3))) void*)l, 16, 0, 0);
}

// ---------------------------------------------------------------------------
// transpose+convert: x [B, C, HW] f32 -> xb [B*HW, C] bf16
// ---------------------------------------------------------------------------
__global__ __launch_bounds__(256) void conv_x(const float* __restrict__ x,
                                              hbf16* __restrict__ xb)
{
  __shared__ float s[32][33];
  const int b   = blockIdx.z;
  const int hw0 = blockIdx.x * 32;
  const int c0  = blockIdx.y * 32;
  const int tx = threadIdx.x & 31, ty = threadIdx.x >> 5;   // 32x8
  #pragma unroll
  for (int i = 0; i < 4; i++) {
    int c = c0 + ty + i * 8;
    s[ty + i * 8][tx] = x[((size_t)b * CIN + c) * HW + hw0 + tx]; // s[c_l][hw_l]
  }
  __syncthreads();
  #pragma unroll
  for (int i = 0; i < 4; i++) {
    int hw = hw0 + ty + i * 8;
    xb[((size_t)b * HW + hw) * CIN + c0 + tx] = __float2bfloat16(s[tx][ty + i * 8]);
  }
}

// ---------------------------------------------------------------------------
// concat weights: wcat rows 0..383 = Wv, 384..1355 = Wa, 1356..1407 = 0
// bcat: 0 for V rows, ba for A rows, 0 for pad
// ---------------------------------------------------------------------------
__global__ __launch_bounds__(256) void prep_wqkv(
    const float* __restrict__ Wv, const float* __restrict__ Wa,
    const float* __restrict__ ba,
    hbf16* __restrict__ wcat, float* __restrict__ bcat)
{
  int i = blockIdx.x * 256 + threadIdx.x;
  if (i < NQKV * CIN) {
    int n = i / CIN, k = i % CIN;
    float v = 0.f;
    if (n < NVAL) v = Wv[(size_t)n * CIN + k];
    else if (n < NVAL + NATT) v = Wa[(size_t)(n - NVAL) * CIN + k];
    wcat[i] = __float2bfloat16(v);
  }
  if (i < NQKV) {
    float bv = 0.f;
    if (i >= NVAL && i < NVAL + NATT) bv = ba[i - NVAL];
    bcat[i] = bv;
  }
}

// ---------------------------------------------------------------------------
// weight convert: src [384,384] f32 -> bf16
// ---------------------------------------------------------------------------
__global__ __launch_bounds__(256) void conv_w(const float* __restrict__ w,
                                              hbf16* __restrict__ wb, int total)
{
  int i = blockIdx.x * 256 + threadIdx.x;
  if (i < total) wb[i] = __float2bfloat16(w[i]);
}

// ---------------------------------------------------------------------------
// Double-buffered MFMA GEMM, 128x128 tile, BK=32, 4 waves.
// MODE 0 (QKV): operand-swapped acc (lane=m, regs=n); epilogue packs bf16,
//   LDS-transposes to [m][n] and streams coalesced rows, routing cols <384
//   to vproj [NPIX,384] and cols >=384 to attn [NPIX, ASTRIDE].
// MODE 1 (P): natural acc (lane=n, regs=m); epilogue LDS-transposes to [n][m]
//   f32 (two m-half passes) and streams out[b, n, hw] coalesced in hw.
// ---------------------------------------------------------------------------
template<int MODE>
__global__ __launch_bounds__(256) void gemm_fused(
    const hbf16* __restrict__ A_,
    const hbf16* __restrict__ Bt_,
    const float* __restrict__ bias,
    hbf16* __restrict__ ovp,      // MODE 0: vproj
    hbf16* __restrict__ oat,      // MODE 0: attn
    float* __restrict__ oput)     // MODE 1: out [B, 384, HW]
{
  __shared__ __align__(16) char smem[33280];  // 2x(As8K+Bs8K)=32K (epi aliases) + 512 bias
  const __bf16* A  = (const __bf16*)A_;
  const __bf16* Bt = (const __bf16*)Bt_;

  const int tid  = threadIdx.x;
  const int wave = tid >> 6, lane = tid & 63;
  const int wr = wave >> 1, wc = wave & 1;
  const int l16 = lane & 15, kg = lane >> 4;
  const int m0 = blockIdx.x * 128, n0 = blockIdx.y * 128;

  float* biasLds = (float*)(smem + 32768);
  if (tid < 128) biasLds[tid] = bias[n0 + tid];

  const int srow = tid >> 2;              // (tid*16)>>6
  const int skb  = (tid & 3) * 16;

  f32x4 acc[4][4] = {};

  auto stage = [&](int k0, int buf) {
    const char* gA = (const char*)(A  + (size_t)m0 * CIN + k0);
    const char* gB = (const char*)(Bt + (size_t)n0 * CIN + k0);
    char* lA = smem + buf * 16384;
    char* lB = smem + buf * 16384 + 8192;
    #pragma unroll
    for (int p = 0; p < 2; p++) {
      int row = p * 64 + srow;
      gload_lds16(gA + (size_t)row * (CIN * 2) + skb, lA + p * 4096 + wave * 1024);
      gload_lds16(gB + (size_t)row * (CIN * 2) + skb, lB + p * 4096 + wave * 1024);
    }
  };

  stage(0, 0);
  __syncthreads();   // drains vmcnt before barrier (compiler-emitted)

  for (int t = 0; t < KSTEPS; ++t) {
    const int buf = t & 1;
    if (t + 1 < KSTEPS) stage((t + 1) * 32, buf ^ 1);   // prefetch overlaps MFMA

    const __bf16* As = (const __bf16*)(smem + buf * 16384);
    const __bf16* Bs = (const __bf16*)(smem + buf * 16384 + 8192);
    bf16x8 af[4], bfr[4];
    #pragma unroll
    for (int mi = 0; mi < 4; mi++)
      af[mi] = *(const bf16x8*)(As + (wr * 64 + mi * 16 + l16) * 32 + kg * 8);
    #pragma unroll
    for (int ni = 0; ni < 4; ni++)
      bfr[ni] = *(const bf16x8*)(Bs + (wc * 64 + ni * 16 + l16) * 32 + kg * 8);
    #pragma unroll
    for (int mi = 0; mi < 4; mi++)
      #pragma unroll
      for (int ni = 0; ni < 4; ni++) {
        if (MODE == 0)   // swapped: lane indexes m, regs index n
          acc[ni][mi] = __builtin_amdgcn_mfma_f32_16x16x32_bf16(
              bfr[ni], af[mi], acc[ni][mi], 0, 0, 0);
        else
          acc[mi][ni] = __builtin_amdgcn_mfma_f32_16x16x32_bf16(
              af[mi], bfr[ni], acc[mi][ni], 0, 0, 0);
      }
    __syncthreads();
  }

  if (MODE == 0) {
    // ---- QKV epilogue: bf16 [m 128][n 128], n XOR-swizzled by ((m&7)<<3) ----
    __bf16* epi = (__bf16*)smem;
    #pragma unroll
    for (int ni = 0; ni < 4; ni++) {
      #pragma unroll
      for (int mi = 0; mi < 4; mi++) {
        const int m  = wr * 64 + mi * 16 + l16;
        const int nb = wc * 64 + ni * 16 + kg * 4;
        bf16x4 v4;
        #pragma unroll
        for (int r = 0; r < 4; r++)
          v4[r] = (__bf16)__float2bfloat16(acc[ni][mi][r] + biasLds[nb + r]);
        *(bf16x4*)(epi + m * 128 + (nb ^ ((m & 7) << 3))) = v4;
      }
    }
    __syncthreads();
    const bool isv = (n0 < NVAL);
    #pragma unroll
    for (int q = 0; q < 8; q++) {
      const int cid = q * 256 + tid;
      const int m = cid >> 4, nc = cid & 15;
      const int nloc = nc * 8;
      bf16x8 v = *(const bf16x8*)(epi + m * 128 + (nloc ^ ((m & 7) << 3)));
      const int mg = m0 + m;
      if (isv) {
        *(bf16x8*)(ovp + (size_t)mg * NVAL + n0 + nloc) = v;
      } else {
        const int a = n0 - NVAL + nloc;
        if (a < NATT)
          *(bf16x8*)(oat + (size_t)mg * ASTRIDE + a) = v;
      }
    }
  } else {
    // ---- P epilogue: f32 [n 128][m_loc 64], m XOR-swizzled by ((n&7)<<2) ----
    float* epi = (float*)smem;
    #pragma unroll
    for (int p = 0; p < 2; p++) {
      if (p) __syncthreads();
      if (wr == p) {
        #pragma unroll
        for (int mi = 0; mi < 4; mi++) {
          #pragma unroll
          for (int ni = 0; ni < 4; ni++) {
            const int n  = wc * 64 + ni * 16 + l16;
            const int ml = mi * 16 + kg * 4;
            f32x4 v;
            #pragma unroll
            for (int r = 0; r < 4; r++) v[r] = acc[mi][ni][r] + biasLds[n];
            *(f32x4*)(epi + n * 64 + (ml ^ ((n & 7) << 2))) = v;
          }
        }
      }
      __syncthreads();
      #pragma unroll
      for (int q = 0; q < 8; q++) {
        const int cid = q * 256 + tid;
        const int n = cid >> 4, mc = cid & 15;
        const int ml = mc * 4;
        f32x4 v = *(const f32x4*)(epi + n * 64 + (ml ^ ((n & 7) << 2)));
        const int mg = m0 + p * 64 + ml;           // 4 | 3136: no batch straddle
        const int b = mg / HW, hw = mg % HW;
        *(f32x4*)(oput + ((size_t)b * NVAL + n0 + n) * HW + hw) = v;
      }
    }
  }
}

// ---------------------------------------------------------------------------
// build_w: collapse softmax(attn) into a 5x5 effective kernel per (pixel,head)
// ---------------------------------------------------------------------------
__global__ __launch_bounds__(256) void build_w(
    const hbf16* __restrict__ attnb,   // [NPIX, ASTRIDE] bf16 logits
    float* __restrict__ Wg)            // [NPIX, 12, 25] f32
{
  int idx = blockIdx.x * 256 + threadIdx.x;
  if (idx >= NPIX * HEADS) return;
  const int pix = idx / HEADS, n = idx % HEADS;
  const int b = pix / HW, yx = pix % HW;
  const int y = yx / WID, x = yx % WID;

  float W[25];
  #pragma unroll
  for (int k = 0; k < 25; k++) W[k] = 0.f;
  const float scale = 0.17677669529663687f; // 32^-0.5

  #pragma unroll
  for (int i = 0; i < 3; i++) {
    #pragma unroll
    for (int j = 0; j < 3; j++) {
      const int hh = y - i + 1, ww = x - j + 1;
      if (hh < 0 || hh >= HGT || ww < 0 || ww >= WID) continue;
      const hbf16* p = attnb +
          (size_t)(b * HW + hh * WID + ww) * ASTRIDE + n * 81 + (i * 3 + j) * 9;
      float v[9];
      float m = -1e30f;
      #pragma unroll
      for (int q = 0; q < 9; q++) {
        v[q] = __bfloat162float(p[q]) * scale;
        m = fmaxf(m, v[q]);
      }
      float s = 0.f;
      #pragma unroll
      for (int q = 0; q < 9; q++) { v[q] = __expf(v[q] - m); s += v[q]; }
      const float inv = 1.f / s;
      #pragma unroll
      for (int ip = 0; ip < 3; ip++)
        #pragma unroll
        for (int jp = 0; jp < 3; jp++)
          W[(ip - i + 2) * 5 + (jp - j + 2)] += v[ip * 3 + jp] * inv;
    }
  }
  float* o = Wg + (size_t)idx * 25;
  #pragma unroll
  for (int k = 0; k < 25; k++) o[k] = W[k];
}

// ---------------------------------------------------------------------------
// apply_fold: folded[pix, c] = sum_{25} W[pix, head(c), a, e] * vproj[gather]
// ---------------------------------------------------------------------------
__global__ __launch_bounds__(384) void apply_fold(
    const float* __restrict__ Wg,      // [NPIX, 12, 25]
    const hbf16* __restrict__ vprojb,  // [NPIX, 384] bf16
    hbf16* __restrict__ foldedb)       // [NPIX, 384] bf16
{
  __shared__ float Wl[PIXB * HEADS * 25];   // 2400 f32

  const int pix0 = blockIdx.x * PIXB;
  const int tid = threadIdx.x;
  for (int r = tid; r < PIXB * HEADS * 25; r += 384)
    Wl[r] = Wg[(size_t)pix0 * HEADS * 25 + r];
  __syncthreads();

  const int p8  = tid / 48;
  const int ch8 = tid % 48;
  const int c0  = ch8 * 8;
  const int n   = c0 >> 5;
  const int pix = pix0 + p8;            // 8 | 56 -> block stays in one row
  const int b = pix / HW, yx = pix % HW;
  const int y = yx / WID, x = yx % WID;

  const float* Wp = &Wl[(p8 * HEADS + n) * 25];
  float acc[8];
  #pragma unroll
  for (int k = 0; k < 8; k++) acc[k] = 0.f;

  #pragma unroll
  for (int a = 0; a < 5; a++) {
    const int wi = y + a - 2;
    #pragma unroll
    for (int e = 0; e < 5; e++) {
      const int hi = x + e - 2;
      if (wi >= 0 && wi < WID && hi >= 0 && hi < HGT) {
        const float w = Wp[a * 5 + e];
        const uint32_t* v = (const uint32_t*)(
            vprojb + ((size_t)b * HW + hi * WID + wi) * NVAL + c0);
        #pragma unroll
        for (int u = 0; u < 4; u++) {
          uint32_t bits = v[u];
          float lo  = __uint_as_float(bits << 16);
          float hif = __uint_as_float(bits & 0xffff0000u);
          acc[2 * u]     += w * lo;
          acc[2 * u + 1] += w * hif;
        }
      }
    }
  }

  bf16x8 o;
  #pragma unroll
  for (int k = 0; k < 8; k++) o[k] = (__bf16)__float2bfloat16(acc[k]);
  *(bf16x8*)(foldedb + (size_t)pix * NVAL + c0) = o;
}

// ---------------------------------------------------------------------------
extern "C" void kernel_launch(void* const* d_in, const int* in_sizes, int n_in,
                              void* d_out, int out_size, void* d_ws, size_t ws_size,
                              hipStream_t stream)
{
  const float* x  = (const float*)d_in[0];
  const float* Wv = (const float*)d_in[1];
  const float* Wa = (const float*)d_in[2];
  const float* ba = (const float*)d_in[3];
  const float* Wp = (const float*)d_in[4];
  const float* bp = (const float*)d_in[5];
  float* out = (float*)d_out;

  char* w = (char*)d_ws;
  const size_t ATTN_B  = (size_t)NPIX * ASTRIDE * 2;    // 49.0 MB
  const size_t VPROJ_B = (size_t)NPIX * NVAL * 2;       // 19.3 MB
  const size_t XB_B    = (size_t)NPIX * CIN * 2;        // 19.3 MB
  const size_t WG_B    = (size_t)NPIX * HEADS * 25 * 4; // 30.1 MB
  hbf16* attnb  = (hbf16*)w;
  hbf16* vprojb = (hbf16*)(w + ATTN_B);
  hbf16* xb     = (hbf16*)(w + ATTN_B + VPROJ_B);
  float* Wg     = (float*)(w + ATTN_B + VPROJ_B + XB_B);
  hbf16* wcat   = (hbf16*)(w + ATTN_B + VPROJ_B + XB_B + WG_B);
  hbf16* wpb    = wcat + (size_t)NQKV * CIN;
  float* bcat   = (float*)(wpb + (size_t)CIN * CIN);
  hbf16* foldedb = xb;            // reuse: xb dead after the QKV GEMM

  // 1) input transpose/convert + weight prep
  conv_x<<<dim3(HW / 32, CIN / 32, BATCH), 256, 0, stream>>>(x, xb);
  prep_wqkv<<<dim3((NQKV * CIN + 255) / 256), 256, 0, stream>>>(
      Wv, Wa, ba, wcat, bcat);
  conv_w<<<dim3((CIN * CIN + 255) / 256), 256, 0, stream>>>(Wp, wpb, CIN * CIN);

  // 2) fused V+A projection: vprojb [pix,384] bf16, attnb [pix,976] bf16
  gemm_fused<0><<<dim3(NPIX / 128, NQKV / 128), 256, 0, stream>>>(
      xb, wcat, bcat, vprojb, attnb, nullptr);
  // 3) softmax + collapse to 5x5 effective kernels
  build_w<<<dim3((NPIX * HEADS + 255) / 256), 256, 0, stream>>>(attnb, Wg);
  // 4) apply 5x5 kernels to vproj -> foldedb bf16
  apply_fold<<<dim3(NPIX / PIXB), dim3(384), 0, stream>>>(Wg, vprojb, foldedb);
  // 5) output projection (+bp), coalesced transpose-out to [B, 384, HW]
  gemm_fused<1><<<dim3(NPIX / 128, NVAL / 128), 256, 0, stream>>>(
      foldedb, wpb, bp, nullptr, nullptr, out);
}